// Round 4
// baseline (218.365 us; speedup 1.0000x reference)
//
#include <hip/hip_runtime.h>
#include <cstdint>
#include <cstddef>

#define BB 16
#define NN 4096
#define CC 80
#define MAXD 100
#define IOU_T 0.5f
#define CONF_T 0.5f
#define RSTRIDE 81
#define PER_B (MAXD * 4 + MAXD * CC)   // 8400 output elems per batch
#define NWORDS (NN / 64)               // 64 bitmap words
#define BCAP 2048                      // group-B sort capacity (B is ~1-5% of N)
#define SEGSZ 2048                     // candidate corners segment (LDS-resident)

// ---------------------------------------------------------------------------
// K1: softmax of (10x)^2 per row, one THREAD per row, 128 rows/block.
// numpy pairwise-8 sum DAG for s (bitwise == np), score = IEEE fl(1/s)
// (decides order); probs use e * fl(1/s) (<=2ulp vs ref, tol 2e-2).
// ---------------------------------------------------------------------------
__global__ __launch_bounds__(128) void k_softmax(const float* __restrict__ cls_in,
                                                 float* __restrict__ probs,
                                                 uint64_t* __restrict__ keys) {
#pragma clang fp contract(off)
    __shared__ float buf[128 * RSTRIDE];
    int t = threadIdx.x;
    size_t gbase = (size_t)blockIdx.x * 128 * CC;

    for (int i = t; i < 128 * CC; i += 128) {
        int r = i / CC, c = i - r * CC;
        buf[r * RSTRIDE + c] = cls_in[gbase + i];
    }
    __syncthreads();

    float* row = buf + t * RSTRIDE;

    float m = -3.402823466e+38f;
    for (int c = 0; c < CC; ++c) {
        float y = row[c] * 10.0f;
        float z = y * y;
        m = fmaxf(m, z);
    }
    for (int c = 0; c < CC; ++c) {
        float y = row[c] * 10.0f;
        float z = y * y;
        row[c] = expf(z - m);
    }
    // numpy pairwise-8 summation DAG (n=80)
    float r8[8];
    #pragma unroll
    for (int j = 0; j < 8; ++j) r8[j] = row[j];
    for (int i = 8; i < CC; i += 8) {
        #pragma unroll
        for (int j = 0; j < 8; ++j) r8[j] += row[i + j];
    }
    float s = ((r8[0] + r8[1]) + (r8[2] + r8[3])) + ((r8[4] + r8[5]) + (r8[6] + r8[7]));

    float score = 1.0f / s;             // exact IEEE divide — decides order
    for (int c = 0; c < CC; ++c) row[c] = row[c] * score;

    int gw = blockIdx.x * 128 + t;
    unsigned n = (unsigned)(gw & (NN - 1));
    keys[gw] = ((uint64_t)__float_as_uint(score) << 32)
             | (uint64_t)(0xFFFFFFFFu - n);

    __syncthreads();
    for (int i = t; i < 128 * CC; i += 128) {
        int r = i / CC, c = i - r * CC;
        probs[gbase + i] = buf[r * RSTRIDE + c];
    }
}

// ---------------------------------------------------------------------------
// K2: fused partition + B-sort + bitmap NMS. One block (1024 thr) per batch.
//  - A = {score==1.0f}: stable compaction in idx order (no sort needed)
//  - B = {0.5<score<1.0}: mini bitonic sort in LDS (<=2048)
//  - C = {score<=0.5}: discarded (never valid -> never kept/suppresses)
//  - walk: t0 scans 4096-bit suppression bitmap; per keep, all threads
//    IOU-suppress the LDS-resident segment in parallel (ballot -> OR).
// Sorted index list stored over the dead keys[] region (no extra ws).
// ---------------------------------------------------------------------------
__global__ __launch_bounds__(1024) void k_nms(uint64_t* keys,
                                              const float* __restrict__ boxes,
                                              int* __restrict__ kidx_out,
                                              int* __restrict__ cnt_out) {
#pragma clang fp contract(off)
    __shared__ float sy1[SEGSZ], sx1[SEGSZ], sy2[SEGSZ], sx2[SEGSZ];
    __shared__ int   soidx[SEGSZ];
    __shared__ uint64_t bbuf[BCAP];
    __shared__ uint64_t sup[NWORDS];
    __shared__ float ky1[MAXD], kx1[MAXD], ky2[MAXD], kx2[MAXD], kar[MAXD];
    __shared__ int   keptidx[MAXD];
    __shared__ int   wsumA[16], wsumB[16];
    __shared__ int   keptcnt_s, ctrl_s, seg_s;

    const int tid = threadIdx.x, lane = tid & 63, wv = tid >> 6;
    const int b = blockIdx.x;
    const uint64_t* kb = keys + (size_t)b * NN;
    const float* bxp = boxes + (size_t)b * NN * 4;
    int* og = (int*)(keys + (size_t)b * NN);   // reuse dead keys region

    // ---- partition: classify + block-wide stable scans ----
    uint64_t myk[4]; bool fa[4], fb[4];
    int asum = 0, bsum = 0;
    for (int k = 0; k < 4; ++k) {
        uint64_t key = kb[4 * tid + k]; myk[k] = key;
        unsigned hi = (unsigned)(key >> 32);
        fa[k] = (hi == 0x3F800000u);
        fb[k] = (__uint_as_float(hi) > CONF_T) && !fa[k];
        asum += fa[k] ? 1 : 0; bsum += fb[k] ? 1 : 0;
    }
    int ia = asum, ib = bsum;                       // wave-inclusive scans
    for (int off = 1; off < 64; off <<= 1) {
        int va = __shfl_up(ia, off), vb = __shfl_up(ib, off);
        if (lane >= off) { ia += va; ib += vb; }
    }
    if (lane == 63) { wsumA[wv] = ia; wsumB[wv] = ib; }
    __syncthreads();
    int baseA = 0, baseB = 0, cntA = 0, cntB = 0;
    for (int w2 = 0; w2 < 16; ++w2) {
        if (w2 < wv) { baseA += wsumA[w2]; baseB += wsumB[w2]; }
        cntA += wsumA[w2]; cntB += wsumB[w2];
    }
    int pA = baseA + (ia - asum);
    int pB = baseB + (ib - bsum);
    for (int k = 0; k < 4; ++k) {
        if (fa[k]) og[pA++] = 4 * tid + k;          // orig idx == position
        if (fb[k]) { if (pB < BCAP) bbuf[pB] = myk[k]; pB++; }
    }
    int cntBc = cntB < BCAP ? cntB : BCAP;
    int nlist = cntA + cntBc;
    if (tid == 0) { keptcnt_s = 0; seg_s = 0; }
    // pad bbuf tail (disjoint slots from scatter)
    for (int i = tid; i < BCAP; i += 1024) if (i >= cntB) bbuf[i] = 0;
    __syncthreads();

    // ---- mini bitonic sort (descending) of B keys ----
    for (unsigned k2 = 2; k2 <= BCAP; k2 <<= 1) {
        for (unsigned j = k2 >> 1; j > 0; j >>= 1) {
            for (unsigned i = tid; i < BCAP; i += 1024) {
                unsigned p = i ^ j;
                if (p > i) {
                    uint64_t va = bbuf[i], vb = bbuf[p];
                    bool desc = ((i & k2) == 0);
                    if (desc ? (va < vb) : (va > vb)) { bbuf[i] = vb; bbuf[p] = va; }
                }
            }
            __syncthreads();
        }
    }
    for (int i = tid; i < cntBc; i += 1024)
        og[cntA + i] = (int)(0xFFFFFFFFu - (unsigned)(bbuf[i] & 0xFFFFFFFFull));
    // sup init: bits >= nlist pre-suppressed
    if (tid < NWORDS) {
        int lo = tid * 64;
        uint64_t mm;
        if (nlist <= lo) mm = ~0ull;
        else if (nlist >= lo + 64) mm = 0ull;
        else mm = (~0ull) << (nlist - lo);
        sup[tid] = mm;
    }
    __syncthreads();

    // ---- preload segment 0 corners ----
    for (int i = tid; i < SEGSZ; i += 1024) {
        if (i < nlist) {
            int o = og[i];
            soidx[i] = o;
            const float* bp = bxp + (size_t)o * 4;
            float b0 = bp[0], b1 = bp[1], b2 = bp[2], b3 = bp[3];
            sy1[i] = fminf(b0, b2); sy2[i] = fmaxf(b0, b2);
            sx1[i] = fminf(b1, b3); sx2[i] = fmaxf(b1, b3);
        }
    }
    __syncthreads();

    // ---- walk ----
    int curw = 0, segr = 0;
    while (true) {
        if (tid == 0) {
            int code = -1;
            for (;;) {
                int wend = (segr + 1) * (SEGSZ / 64);
                if (curw >= wend) {
                    if (segr == 0 && nlist > SEGSZ) {
                        code = -2; segr = 1; seg_s = 1; curw = SEGSZ / 64;
                    } else code = -1;
                    break;
                }
                uint64_t live = ~sup[curw];
                if (live) {
                    int j = __ffsll((unsigned long long)live) - 1;
                    int sel = curw * 64 + j;
                    int li = sel - segr * SEGSZ;
                    int kc = keptcnt_s;
                    keptidx[kc] = soidx[li];
                    ky1[kc] = sy1[li]; kx1[kc] = sx1[li];
                    ky2[kc] = sy2[li]; kx2[kc] = sx2[li];
                    kar[kc] = (sy2[li] - sy1[li]) * (sx2[li] - sx1[li]);
                    keptcnt_s = kc + 1;
                    sup[curw] |= (1ull << j);       // self-guard (zero-area boxes)
                    code = (kc + 1 >= MAXD) ? -1 : sel;
                    break;
                }
                ++curw;
            }
            ctrl_s = code;
        }
        __syncthreads();
        int c = ctrl_s;
        if (c == -1) break;

        if (c == -2) {
            // preload segment 1
            for (int i = tid; i < SEGSZ; i += 1024) {
                int gi = SEGSZ + i;
                if (gi < nlist) {
                    int o = og[gi];
                    soidx[i] = o;
                    const float* bp = bxp + (size_t)o * 4;
                    float b0 = bp[0], b1 = bp[1], b2 = bp[2], b3 = bp[3];
                    sy1[i] = fminf(b0, b2); sy2[i] = fmaxf(b0, b2);
                    sx1[i] = fminf(b1, b3); sx2[i] = fmaxf(b1, b3);
                }
            }
            __syncthreads();
            // batch-suppress segment 1 vs all kept so far
            int kc = keptcnt_s;
            for (int k = 0; k < 2; ++k) {
                int li = tid + k * 1024;
                float y1 = sy1[li], y2 = sy2[li], x1 = sx1[li], x2 = sx2[li];
                float ar = (y2 - y1) * (x2 - x1);
                bool s = false;
                for (int q = 0; q < kc; ++q) {
                    float ih = fmaxf(0.f, fminf(y2, ky2[q]) - fmaxf(y1, ky1[q]));
                    float iw = fmaxf(0.f, fminf(x2, kx2[q]) - fmaxf(x1, kx1[q]));
                    float inter = ih * iw;
                    float uni = (ar + kar[q]) - inter;
                    s = s || (inter > 0.f && inter / uni > IOU_T);
                }
                uint64_t bal = __ballot(s);
                if (lane == 0 && bal) {
                    int word = (SEGSZ + k * 1024 + wv * 64) >> 6;  // unique per (k,wv)
                    sup[word] |= bal;
                }
            }
            __syncthreads();
            continue;
        }

        // keep-op: suppress current segment vs kept candidate c
        int sg = seg_s;
        int cl = c - sg * SEGSZ;
        float cy1 = sy1[cl], cy2 = sy2[cl], cx1 = sx1[cl], cx2 = sx2[cl];
        float car = (cy2 - cy1) * (cx2 - cx1);
        for (int k = 0; k < 2; ++k) {
            int li = tid + k * 1024;
            float y1 = sy1[li], y2 = sy2[li], x1 = sx1[li], x2 = sx2[li];
            float ar = (y2 - y1) * (x2 - x1);
            float ih = fmaxf(0.f, fminf(y2, cy2) - fmaxf(y1, cy1));
            float iw = fmaxf(0.f, fminf(x2, cx2) - fmaxf(x1, cx1));
            float inter = ih * iw;
            float uni = (ar + car) - inter;
            bool s = (inter > 0.f) && (inter / uni > IOU_T);
            uint64_t bal = __ballot(s);
            if (lane == 0 && bal) {
                int word = (sg * SEGSZ + k * 1024 + wv * 64) >> 6;
                sup[word] |= bal;
            }
        }
        __syncthreads();
    }

    if (tid == 0) cnt_out[b] = keptcnt_s;
    for (int i = tid; i < MAXD; i += 1024)
        kidx_out[b * MAXD + i] = (i < keptcnt_s) ? keptidx[i] : 0;
}

// ---------------------------------------------------------------------------
// K3: wide parallel gather. One thread per output element.
// ---------------------------------------------------------------------------
__global__ __launch_bounds__(256) void k_gather(const float* __restrict__ boxes,
                                                const float* __restrict__ probs,
                                                const int* __restrict__ kidx,
                                                const int* __restrict__ cnt,
                                                float* __restrict__ out_box,
                                                float* __restrict__ out_cls) {
    int u = blockIdx.x * 256 + threadIdx.x;
    if (u >= BB * PER_B) return;
    int b = u / PER_B;
    int r = u - b * PER_B;
    int count = cnt[b];
    float val = 0.0f;
    if (r < MAXD * 4) {
        int t = r >> 2, e = r & 3;
        if (t < count) {
            int idx = kidx[b * MAXD + t];
            val = boxes[((size_t)b * NN + idx) * 4 + e];
        }
        out_box[(size_t)b * MAXD * 4 + r] = val;
    } else {
        int q = r - MAXD * 4;
        int t = q / CC, c = q - t * CC;
        if (t < count) {
            int idx = kidx[b * MAXD + t];
            val = probs[((size_t)b * NN + idx) * CC + c];
        }
        out_cls[(size_t)b * MAXD * CC + q] = val;
    }
}

extern "C" void kernel_launch(void* const* d_in, const int* in_sizes, int n_in,
                              void* d_out, int out_size, void* d_ws, size_t ws_size,
                              hipStream_t stream) {
    const float* boxes = (const float*)d_in[0];   // [B,N,4]
    const float* cls   = (const float*)d_in[1];   // [B,N,C]
    float* out = (float*)d_out;
    float* out_box = out;                                                  // [B,100,4]
    float* out_cls = out + (size_t)BB * MAXD * 4;                          // [B,100,80]
    float* probs   = out + (size_t)BB * MAXD * 4 + (size_t)BB * MAXD * CC; // [B,N,80]

    uint64_t* keys = (uint64_t*)d_ws;                                      // [B,N] (reused as sorted-idx list)
    int* kidx = (int*)((char*)d_ws + (size_t)BB * NN * sizeof(uint64_t));  // [B,100]
    int* cnt  = kidx + BB * MAXD;                                          // [B]

    k_softmax<<<(BB * NN) / 128, 128, 0, stream>>>(cls, probs, keys);
    k_nms<<<BB, 1024, 0, stream>>>(keys, boxes, kidx, cnt);
    k_gather<<<(BB * PER_B + 255) / 256, 256, 0, stream>>>(boxes, probs, kidx, cnt,
                                                           out_box, out_cls);
}